// Round 5
// baseline (998.442 us; speedup 1.0000x reference)
//
#include <hip/hip_runtime.h>

// ---------------------------------------------------------------------------
// LoRA QKV: out_p = x @ (W_p + B_p @ A_p)^T  for p in {q,k,v}
// M = 8192, N = 4096 per proj (x3), K = 4096.
// Fold LoRA into weights (exact), convert to bf16 (one merged prep kernel),
// fused 3-proj GEMM: m201 256x256 8-phase schedule, mfma_f32_32x32x16_bf16.
// ---------------------------------------------------------------------------

typedef __bf16 bf16x8 __attribute__((ext_vector_type(8)));
typedef float f32x16 __attribute__((ext_vector_type(16)));

#define GLL16(g, l)                                                        \
  __builtin_amdgcn_global_load_lds(                                        \
      (const __attribute__((address_space(1))) unsigned int*)(g),          \
      (__attribute__((address_space(3))) unsigned int*)(l), 16, 0, 0)

#define BAR()                                                              \
  {                                                                        \
    __builtin_amdgcn_sched_barrier(0);                                     \
    __builtin_amdgcn_s_barrier();                                          \
  }
#define WLG(n) asm volatile("s_waitcnt lgkmcnt(" #n ")" ::: "memory")
#define WVM(n) asm volatile("s_waitcnt vmcnt(" #n ")" ::: "memory")

#define LDV(p) (*reinterpret_cast<const bf16x8*>(p))

// read 2 A m-tiles (M0, M0+1), all 4 k-substeps, into dst[2][4]  (8 reads)
#define RDA2(dst, base, M0)                                                \
  _Pragma("unroll") for (int mm = 0; mm < 2; ++mm) {                       \
    dst[mm][0] = LDV((base) + ((M0) + mm) * 2048 + swk0);                  \
    dst[mm][1] = LDV((base) + ((M0) + mm) * 2048 + swk1);                  \
    dst[mm][2] = LDV((base) + ((M0) + mm) * 2048 + swk2);                  \
    dst[mm][3] = LDV((base) + ((M0) + mm) * 2048 + swk3);                  \
  }
// read 1 B n-tile (NT), all 4 k-substeps, into dst[4]  (4 reads)
#define RDB4(dst, base, NT)                                                \
  {                                                                        \
    dst[0] = LDV((base) + (NT)*2048 + swk0);                               \
    dst[1] = LDV((base) + (NT)*2048 + swk1);                               \
    dst[2] = LDV((base) + (NT)*2048 + swk2);                               \
    dst[3] = LDV((base) + (NT)*2048 + swk3);                               \
  }

// one C-quadrant (m-pair MP, n-tile NT) x K=64: 8 MFMAs, setprio-wrapped
#define MFQ(AQ, BQ, MP, NT)                                                \
  {                                                                        \
    __builtin_amdgcn_s_setprio(1);                                         \
    _Pragma("unroll") for (int ks = 0; ks < 4; ++ks)                       \
        _Pragma("unroll") for (int mm = 0; mm < 2; ++mm)                   \
            acc[(MP)*2 + mm][NT] =                                         \
                __builtin_amdgcn_mfma_f32_32x32x16_bf16(                   \
                    AQ[mm][ks], BQ[ks], acc[(MP)*2 + mm][NT], 0, 0, 0);    \
    __builtin_amdgcn_s_setprio(0);                                         \
  }

// stage one 16KB half-tile (2 loads/thread). h = 128-row half, ko = K elem.
#define STG_A(db, h, ko)                                                   \
  {                                                                        \
    GLL16(sa + (size_t)((h)*128) * 4096 + (ko),                            \
          (char*)smem + (db)*65536 + (h)*16384 + tid * 16);                \
    GLL16(sa + (size_t)((h)*128 + 64) * 4096 + (ko),                       \
          (char*)smem + (db)*65536 + (h)*16384 + 8192 + tid * 16);         \
  }
#define STG_B(db, h, ko)                                                   \
  {                                                                        \
    GLL16(sb + (size_t)((h)*128) * 4096 + (ko),                            \
          (char*)smem + (db)*65536 + 32768 + (h)*16384 + tid * 16);        \
    GLL16(sb + (size_t)((h)*128 + 64) * 4096 + (ko),                       \
          (char*)smem + (db)*65536 + 32768 + (h)*16384 + 8192 + tid * 16); \
  }

__device__ __forceinline__ unsigned int f2b(float f) {
  unsigned int u = __builtin_bit_cast(unsigned int, f);
  u += 0x7FFFu + ((u >> 16) & 1u);
  return u >> 16;
}

// ---------------------------------------------------------------------------
// Prep (single launch): blocks 0..8191 convert x -> bf16 (16 elems/thread);
// blocks 8192..32767 fold W' = W + B@A for proj 0..2 (8192 blocks each).
// ---------------------------------------------------------------------------
__global__ void prep_kernel(const float* __restrict__ x,
                            const float* __restrict__ w0,
                            const float* __restrict__ w1,
                            const float* __restrict__ w2,
                            const float* __restrict__ a0,
                            const float* __restrict__ b0,
                            const float* __restrict__ a1,
                            const float* __restrict__ b1,
                            const float* __restrict__ a2,
                            const float* __restrict__ b2,
                            unsigned short* __restrict__ xb,
                            unsigned short* __restrict__ wb) {
  const int bid = blockIdx.x;
  const int tid = threadIdx.x;
  if (bid < 8192) {
    // cvt: 2 uint4 outputs (16 elems) per thread
    long base = ((long)bid * 256 + tid) * 2;
    const float4* xp = reinterpret_cast<const float4*>(x) + base * 2;
#pragma unroll
    for (int j = 0; j < 2; ++j) {
      float4 v0 = xp[2 * j];
      float4 v1 = xp[2 * j + 1];
      uint4 o;
      o.x = f2b(v0.x) | (f2b(v0.y) << 16);
      o.y = f2b(v0.z) | (f2b(v0.w) << 16);
      o.z = f2b(v1.x) | (f2b(v1.y) << 16);
      o.w = f2b(v1.z) | (f2b(v1.w) << 16);
      reinterpret_cast<uint4*>(xb)[base + j] = o;
    }
  } else {
    const int fb = bid - 8192;
    const int proj = fb >> 13;  // 0..2
    const float* W = (proj == 0) ? w0 : ((proj == 1) ? w1 : w2);
    const float* Amat = (proj == 0) ? a0 : ((proj == 1) ? a1 : a2);
    const float* Bmat = (proj == 0) ? b0 : ((proj == 1) ? b1 : b2);
    unsigned short* Wo = wb + (size_t)proj * 16777216UL;
    int gi = (fb & 8191) * 256 + tid;
    int d0 = (gi & 511) * 8;
    int h = gi >> 9;
    const float4* wp =
        reinterpret_cast<const float4*>(W + (size_t)h * 4096 + d0);
    float4 w0v = wp[0], w1v = wp[1];
    float acc[8] = {w0v.x, w0v.y, w0v.z, w0v.w, w1v.x, w1v.y, w1v.z, w1v.w};
    const float* bh = Bmat + h * 16;
#pragma unroll
    for (int r = 0; r < 16; ++r) {
      float bv = bh[r];
      const float4* ap =
          reinterpret_cast<const float4*>(Amat + (size_t)r * 4096 + d0);
      float4 A0 = ap[0], A1 = ap[1];
      acc[0] += bv * A0.x; acc[1] += bv * A0.y;
      acc[2] += bv * A0.z; acc[3] += bv * A0.w;
      acc[4] += bv * A1.x; acc[5] += bv * A1.y;
      acc[6] += bv * A1.z; acc[7] += bv * A1.w;
    }
    uint4 o;
    o.x = f2b(acc[0]) | (f2b(acc[1]) << 16);
    o.y = f2b(acc[2]) | (f2b(acc[3]) << 16);
    o.z = f2b(acc[4]) | (f2b(acc[5]) << 16);
    o.w = f2b(acc[6]) | (f2b(acc[7]) << 16);
    reinterpret_cast<uint4*>(Wo)[gi] = o;
  }
}

// ---------------------------------------------------------------------------
// GEMM: 256x256 tile, 8-phase m201 schedule, mfma_f32_32x32x16_bf16.
//   C[M, N*3] = Xb[M,K] @ Wb[3][N,K]^T
// 512 threads = 8 waves (2M x 4N), wave tile 128x64 = 4m x 2n 32x32 tiles.
// BK=64 = 4 x K16 substeps. LDS 128 KiB = 2 dbuf x {A 2x16KB | B 2x16KB}.
// 16B-slot XOR swizzle (phys slot s of row r holds global slot s^(r&7));
// within a 128-row half the layout is linear row*64 elems.
// Phase = { quadrant ds_reads (12/4/8/0) | 1 half-tile stage } -> barrier ->
// lgkmcnt(0) -> setprio(1) 8 MFMA setprio(0) -> barrier.
// Stage map (vmcnt(6)@P4/P8 ledger, depth-3):
//   P1: D1cur.A1 | P2: N0.B0 | P3: N0.B1 | P4: N0.A0 +vm(6)
//   P5: N0.A1    | P6: N1.B0 | P7: N1.B1 | P8: N1.A0 +vm(6)
// ---------------------------------------------------------------------------
__global__ __launch_bounds__(512, 2) void gemm_kernel(
    const unsigned short* __restrict__ Xb,
    const unsigned short* __restrict__ Wb, float* __restrict__ out) {
  __shared__ unsigned short smem[65536];  // 128 KiB

  const int tid = threadIdx.x;
  const int lane = tid & 63;
  const int wid = tid >> 6;
  const int wm = wid >> 2;  // 0..1
  const int wn = wid & 3;   // 0..3

  int bid = blockIdx.x;                    // 1536 = 3 proj * 32 brow * 16 bcol
  int swz = (bid & 7) * 192 + (bid >> 3);  // bijective XCD swizzle
  int p = swz >> 9;
  int r = swz & 511;
  int brow = r >> 4;  // 0..31
  int bcol = r & 15;  // 0..15

  const unsigned short* GA = Xb + (size_t)brow * 256 * 4096;
  const unsigned short* GB =
      Wb + (size_t)p * 16777216UL + (size_t)bcol * 256 * 4096;

  // staging source, pre-swizzled so LDS[r][s] holds global[r][s^(r&7)]
  const int srow = tid >> 3;
  const int sslot = (tid & 7) ^ (srow & 7);
  const unsigned short* sa = GA + (size_t)srow * 4096 + sslot * 8;
  const unsigned short* sb = GB + (size_t)srow * 4096 + sslot * 8;

  // fragment reads: A row = wm*128 + mt*32 + (lane&31); k = ks*16 + (lane>>5)*8
  // linear slot = ks*2 + (lane>>5), phys slot = linear ^ (row&7) = ^ (lane&7)
  const int l31 = lane & 31;
  const int h2 = lane >> 5;
  const int bx = lane & 7;
  const int swk0 = (((0 * 2 + h2) ^ bx)) * 8;
  const int swk1 = (((1 * 2 + h2) ^ bx)) * 8;
  const int swk2 = (((2 * 2 + h2) ^ bx)) * 8;
  const int swk3 = (((3 * 2 + h2) ^ bx)) * 8;
  const __bf16* sm = (const __bf16*)smem;
  const __bf16* arA0 = sm + wm * 8192 + l31 * 64;
  const __bf16* arB0 =
      sm + 16384 + (wn >> 1) * 8192 + ((wn & 1) * 64 + l31) * 64;
  const __bf16* arA1 = arA0 + 32768;
  const __bf16* arB1 = arB0 + 32768;

  f32x16 acc[4][2];
#pragma unroll
  for (int m = 0; m < 4; ++m)
#pragma unroll
    for (int n = 0; n < 2; ++n)
#pragma unroll
      for (int e = 0; e < 16; ++e) acc[m][n][e] = 0.f;

  // prologue (ledger order B0,B1,A0,A1):
  STG_B(0, 0, 0); STG_B(0, 1, 0); STG_A(0, 0, 0); STG_A(0, 1, 0);
  WVM(4);
  STG_B(1, 0, 64); STG_B(1, 1, 64); STG_A(1, 0, 64);
  WVM(6);  // tile0 complete; 6 of tile1 in flight
  BAR();

  bf16x8 aLo[2][4], aHi[2][4], bLo[4], bHi[4];

  for (int i = 0; i < 32; ++i) {
    const bool st = (i < 31);
    const size_t koD1 = (size_t)(2 * i + 1) * 64;
    const size_t koN0 = (size_t)(2 * i + 2) * 64;
    const size_t koN1 = (size_t)(2 * i + 3) * 64;

    // ================= D0 (tile 2i) =================
    // P1: q(m01,n0) reads 12; finish current D1 (A1)
    RDA2(aLo, arA0, 0);
    RDB4(bLo, arB0, 0);
    STG_A(1, 1, koD1);
    WLG(8);
    BAR();
    WLG(0);
    MFQ(aLo, bLo, 0, 0);
    BAR();
    // P2: q(m01,n1) reads 4; stage N0.B0
    RDB4(bHi, arB0, 1);
    if (st) STG_B(0, 0, koN0);
    BAR();
    WLG(0);
    MFQ(aLo, bHi, 0, 1);
    BAR();
    // P3: q(m23,n1) reads 8; stage N0.B1
    RDA2(aHi, arA0, 2);
    if (st) STG_B(0, 1, koN0);
    BAR();
    WLG(0);
    MFQ(aHi, bHi, 1, 1);
    BAR();
    // P4: q(m23,n0) 0 reads; stage N0.A0; vm(6) -> D1 fully landed
    if (st) {
      STG_A(0, 0, koN0);
      WVM(6);
    } else {
      WVM(0);
    }
    BAR();
    MFQ(aHi, bLo, 1, 0);
    BAR();

    // ================= D1 (tile 2i+1) =================
    // P5
    RDA2(aLo, arA1, 0);
    RDB4(bLo, arB1, 0);
    if (st) STG_A(0, 1, koN0);
    WLG(8);
    BAR();
    WLG(0);
    MFQ(aLo, bLo, 0, 0);
    BAR();
    // P6
    RDB4(bHi, arB1, 1);
    if (st) STG_B(1, 0, koN1);
    BAR();
    WLG(0);
    MFQ(aLo, bHi, 0, 1);
    BAR();
    // P7
    RDA2(aHi, arA1, 2);
    if (st) STG_B(1, 1, koN1);
    BAR();
    WLG(0);
    MFQ(aHi, bHi, 1, 1);
    BAR();
    // P8: stage N1.A0; vm(6) -> N0 fully landed
    if (st) {
      STG_A(1, 0, koN1);
      WVM(6);
    }
    BAR();
    MFQ(aHi, bLo, 1, 0);
    BAR();
  }

  // epilogue: 32x32 C/D layout col = lane&31, row = (reg&3)+8*(reg>>2)+4*h2
  float* Cp = out + (size_t)p * 33554432UL +
              ((size_t)(brow * 256 + wm * 128 + 4 * h2)) * 4096 +
              (bcol * 256 + wn * 64 + l31);
#pragma unroll
  for (int mt = 0; mt < 4; ++mt)
#pragma unroll
    for (int nt = 0; nt < 2; ++nt) {
      const f32x16 v = acc[mt][nt];
#pragma unroll
      for (int reg = 0; reg < 16; ++reg) {
        const int row = mt * 32 + (reg & 3) + 8 * (reg >> 2);
        Cp[(size_t)row * 4096 + nt * 32] = v[reg];
      }
    }
}

// ---------------------------------------------------------------------------
extern "C" void kernel_launch(void* const* d_in, const int* in_sizes, int n_in,
                              void* d_out, int out_size, void* d_ws,
                              size_t ws_size, hipStream_t stream) {
  const float* x = (const float*)d_in[0];
  const float* wq = (const float*)d_in[1];
  const float* wk = (const float*)d_in[2];
  const float* wv = (const float*)d_in[3];
  const float* qa = (const float*)d_in[4];
  const float* qb = (const float*)d_in[5];
  const float* ka = (const float*)d_in[6];
  const float* kb = (const float*)d_in[7];
  const float* va = (const float*)d_in[8];
  const float* vb = (const float*)d_in[9];

  unsigned short* xb = (unsigned short*)d_ws;  // 67 MB
  unsigned short* wb = xb + 8192UL * 4096UL;   // 100 MB

  prep_kernel<<<32768, 256, 0, stream>>>(x, wq, wk, wv, qa, qb, ka, kb, va,
                                         vb, xb, wb);
  gemm_kernel<<<1536, 512, 0, stream>>>(xb, wb, (float*)d_out);
}

// Round 6
// 953.942 us; speedup vs baseline: 1.0466x; 1.0466x over previous
//
#include <hip/hip_runtime.h>

// ---------------------------------------------------------------------------
// LoRA QKV: out_p = x @ (W_p + B_p @ A_p)^T  for p in {q,k,v}
// M = 8192, N = 4096 per proj (x3), K = 4096.
// Fold LoRA into weights (exact), convert to bf16 (one merged prep kernel),
// fused 3-proj GEMM: m201 256x256 8-phase schedule, mfma_f32_32x32x16_bf16,
// conflict-free rho-swizzle (phys slot = lin ^ (r&7) ^ ((r>>4)&1)).
// ---------------------------------------------------------------------------

typedef __bf16 bf16x8 __attribute__((ext_vector_type(8)));
typedef float f32x16 __attribute__((ext_vector_type(16)));

#define GLL16(g, l)                                                        \
  __builtin_amdgcn_global_load_lds(                                        \
      (const __attribute__((address_space(1))) unsigned int*)(g),          \
      (__attribute__((address_space(3))) unsigned int*)(l), 16, 0, 0)

#define BAR()                                                              \
  {                                                                        \
    __builtin_amdgcn_sched_barrier(0);                                     \
    __builtin_amdgcn_s_barrier();                                          \
  }
#define WLG(n) asm volatile("s_waitcnt lgkmcnt(" #n ")" ::: "memory")
#define WVM(n) asm volatile("s_waitcnt vmcnt(" #n ")" ::: "memory")

#define LDV(p) (*reinterpret_cast<const bf16x8*>(p))

// read 2 A m-tiles (M0, M0+1), all 4 k-substeps, into dst[2][4]  (8 reads)
#define RDA2(dst, base, M0)                                                \
  _Pragma("unroll") for (int mm = 0; mm < 2; ++mm) {                       \
    dst[mm][0] = LDV((base) + ((M0) + mm) * 2048 + swk0);                  \
    dst[mm][1] = LDV((base) + ((M0) + mm) * 2048 + swk1);                  \
    dst[mm][2] = LDV((base) + ((M0) + mm) * 2048 + swk2);                  \
    dst[mm][3] = LDV((base) + ((M0) + mm) * 2048 + swk3);                  \
  }
// read 1 B n-tile (NT), all 4 k-substeps, into dst[4]  (4 reads)
#define RDB4(dst, base, NT)                                                \
  {                                                                        \
    dst[0] = LDV((base) + (NT)*2048 + swk0);                               \
    dst[1] = LDV((base) + (NT)*2048 + swk1);                               \
    dst[2] = LDV((base) + (NT)*2048 + swk2);                               \
    dst[3] = LDV((base) + (NT)*2048 + swk3);                               \
  }

// one C-quadrant (m-pair MP, n-tile NT) x K=64: 8 MFMAs, setprio-wrapped
#define MFQ(AQ, BQ, MP, NT)                                                \
  {                                                                        \
    __builtin_amdgcn_s_setprio(1);                                         \
    _Pragma("unroll") for (int ks = 0; ks < 4; ++ks)                       \
        _Pragma("unroll") for (int mm = 0; mm < 2; ++mm)                   \
            acc[(MP)*2 + mm][NT] =                                         \
                __builtin_amdgcn_mfma_f32_32x32x16_bf16(                   \
                    AQ[mm][ks], BQ[ks], acc[(MP)*2 + mm][NT], 0, 0, 0);    \
    __builtin_amdgcn_s_setprio(0);                                         \
  }

// stage one 16KB half-tile (2 loads/thread). h = 128-row half, ko = K elem.
#define STG_A(db, h, ko)                                                   \
  {                                                                        \
    GLL16(sa + (size_t)((h)*128) * 4096 + (ko),                            \
          (char*)smem + (db)*65536 + (h)*16384 + tid * 16);                \
    GLL16(sa + (size_t)((h)*128 + 64) * 4096 + (ko),                       \
          (char*)smem + (db)*65536 + (h)*16384 + 8192 + tid * 16);         \
  }
#define STG_B(db, h, ko)                                                   \
  {                                                                        \
    GLL16(sb + (size_t)((h)*128) * 4096 + (ko),                            \
          (char*)smem + (db)*65536 + 32768 + (h)*16384 + tid * 16);        \
    GLL16(sb + (size_t)((h)*128 + 64) * 4096 + (ko),                       \
          (char*)smem + (db)*65536 + 32768 + (h)*16384 + 8192 + tid * 16); \
  }

__device__ __forceinline__ unsigned int f2b(float f) {
  unsigned int u = __builtin_bit_cast(unsigned int, f);
  u += 0x7FFFu + ((u >> 16) & 1u);
  return u >> 16;
}

// ---------------------------------------------------------------------------
// Prep (single launch): blocks 0..8191 convert x -> bf16 (16 elems/thread);
// blocks 8192..32767 fold W' = W + B@A for proj 0..2 (8192 blocks each).
// ---------------------------------------------------------------------------
__global__ void prep_kernel(const float* __restrict__ x,
                            const float* __restrict__ w0,
                            const float* __restrict__ w1,
                            const float* __restrict__ w2,
                            const float* __restrict__ a0,
                            const float* __restrict__ b0,
                            const float* __restrict__ a1,
                            const float* __restrict__ b1,
                            const float* __restrict__ a2,
                            const float* __restrict__ b2,
                            unsigned short* __restrict__ xb,
                            unsigned short* __restrict__ wb) {
  const int bid = blockIdx.x;
  const int tid = threadIdx.x;
  if (bid < 8192) {
    // cvt: 2 uint4 outputs (16 elems) per thread
    long base = ((long)bid * 256 + tid) * 2;
    const float4* xp = reinterpret_cast<const float4*>(x) + base * 2;
#pragma unroll
    for (int j = 0; j < 2; ++j) {
      float4 v0 = xp[2 * j];
      float4 v1 = xp[2 * j + 1];
      uint4 o;
      o.x = f2b(v0.x) | (f2b(v0.y) << 16);
      o.y = f2b(v0.z) | (f2b(v0.w) << 16);
      o.z = f2b(v1.x) | (f2b(v1.y) << 16);
      o.w = f2b(v1.z) | (f2b(v1.w) << 16);
      reinterpret_cast<uint4*>(xb)[base + j] = o;
    }
  } else {
    const int fb = bid - 8192;
    const int proj = fb >> 13;  // 0..2
    const float* W = (proj == 0) ? w0 : ((proj == 1) ? w1 : w2);
    const float* Amat = (proj == 0) ? a0 : ((proj == 1) ? a1 : a2);
    const float* Bmat = (proj == 0) ? b0 : ((proj == 1) ? b1 : b2);
    unsigned short* Wo = wb + (size_t)proj * 16777216UL;
    int gi = (fb & 8191) * 256 + tid;
    int d0 = (gi & 511) * 8;
    int h = gi >> 9;
    const float4* wp =
        reinterpret_cast<const float4*>(W + (size_t)h * 4096 + d0);
    float4 w0v = wp[0], w1v = wp[1];
    float acc[8] = {w0v.x, w0v.y, w0v.z, w0v.w, w1v.x, w1v.y, w1v.z, w1v.w};
    const float* bh = Bmat + h * 16;
#pragma unroll
    for (int r = 0; r < 16; ++r) {
      float bv = bh[r];
      const float4* ap =
          reinterpret_cast<const float4*>(Amat + (size_t)r * 4096 + d0);
      float4 A0 = ap[0], A1 = ap[1];
      acc[0] += bv * A0.x; acc[1] += bv * A0.y;
      acc[2] += bv * A0.z; acc[3] += bv * A0.w;
      acc[4] += bv * A1.x; acc[5] += bv * A1.y;
      acc[6] += bv * A1.z; acc[7] += bv * A1.w;
    }
    uint4 o;
    o.x = f2b(acc[0]) | (f2b(acc[1]) << 16);
    o.y = f2b(acc[2]) | (f2b(acc[3]) << 16);
    o.z = f2b(acc[4]) | (f2b(acc[5]) << 16);
    o.w = f2b(acc[6]) | (f2b(acc[7]) << 16);
    reinterpret_cast<uint4*>(Wo)[gi] = o;
  }
}

// ---------------------------------------------------------------------------
// GEMM: 256x256 tile, 8-phase m201 schedule, mfma_f32_32x32x16_bf16.
//   C[M, N*3] = Xb[M,K] @ Wb[3][N,K]^T
// 512 threads = 8 waves (2M x 4N), wave tile 128x64 = 4m x 2n 32x32 tiles.
// BK=64 = 4 x K16 substeps. LDS 128 KiB = 2 dbuf x {A 2x16KB | B 2x16KB}.
//
// LDS swizzle (conflict-fix vs r5): phys 16B-slot p of row r holds global
// slot p ^ rho(r), rho(r) = (r&7) ^ ((r>>4)&1). The extra (r>>4)&1 bit makes
// the per-ds_read lane->bank-column profile identical to the r4 pattern that
// measured 0 conflicts (two interleaved XOR-families per 32-lane phase, max
// 2 lanes per 16B column), instead of r5's 4-lane collisions (7.55e7 cyc).
// Involution, row-local => same formula on stage-source and read (rule #21).
//
// Phase = { quadrant ds_reads (12/4/8/0) | 1 half-tile stage } -> barrier ->
// lgkmcnt(0) -> setprio(1) 8 MFMA setprio(0) -> barrier.
// Stage map (vmcnt(6)@P4/P8 ledger, depth-3):
//   P1: D1cur.A1 | P2: N0.B0 | P3: N0.B1 | P4: N0.A0 +vm(6)
//   P5: N0.A1    | P6: N1.B0 | P7: N1.B1 | P8: N1.A0 +vm(6)
// ---------------------------------------------------------------------------
__global__ __launch_bounds__(512, 2) void gemm_kernel(
    const unsigned short* __restrict__ Xb,
    const unsigned short* __restrict__ Wb, float* __restrict__ out) {
  __shared__ unsigned short smem[65536];  // 128 KiB

  const int tid = threadIdx.x;
  const int lane = tid & 63;
  const int wid = tid >> 6;
  const int wm = wid >> 2;  // 0..1
  const int wn = wid & 3;   // 0..3

  int bid = blockIdx.x;                    // 1536 = 3 proj * 32 brow * 16 bcol
  int swz = (bid & 7) * 192 + (bid >> 3);  // bijective XCD swizzle
  int p = swz >> 9;
  int r = swz & 511;
  int brow = r >> 4;  // 0..31
  int bcol = r & 15;  // 0..15

  const unsigned short* GA = Xb + (size_t)brow * 256 * 4096;
  const unsigned short* GB =
      Wb + (size_t)p * 16777216UL + (size_t)bcol * 256 * 4096;

  // staging source, pre-swizzled: thread (srow, tid&7) must fetch global slot
  // (tid&7) ^ rho(srow), rho(r) = (r&7)^((r>>4)&1)  [row-local, involution]
  const int srow = tid >> 3;
  const int sslot = (tid & 7) ^ (srow & 7) ^ ((srow >> 4) & 1);
  const unsigned short* sa = GA + (size_t)srow * 4096 + sslot * 8;
  const unsigned short* sb = GB + (size_t)srow * 4096 + sslot * 8;

  // fragment reads: A row (in half) = mt*32 + l31; k = ks*16 + h2*8
  // linear slot = 2ks + h2; phys = lin ^ rho(row), rho(row) = (l31&7)^((l31>>4)&1)
  const int l31 = lane & 31;
  const int h2 = lane >> 5;
  const int rx = (lane & 7) ^ ((l31 >> 4) & 1);
  const int swk0 = ((0 * 2 + h2) ^ rx) * 8;
  const int swk1 = ((1 * 2 + h2) ^ rx) * 8;
  const int swk2 = ((2 * 2 + h2) ^ rx) * 8;
  const int swk3 = ((3 * 2 + h2) ^ rx) * 8;
  const __bf16* sm = (const __bf16*)smem;
  const __bf16* arA0 = sm + wm * 8192 + l31 * 64;
  const __bf16* arB0 =
      sm + 16384 + (wn >> 1) * 8192 + ((wn & 1) * 64 + l31) * 64;
  const __bf16* arA1 = arA0 + 32768;
  const __bf16* arB1 = arB0 + 32768;

  f32x16 acc[4][2];
#pragma unroll
  for (int m = 0; m < 4; ++m)
#pragma unroll
    for (int n = 0; n < 2; ++n)
#pragma unroll
      for (int e = 0; e < 16; ++e) acc[m][n][e] = 0.f;

  // prologue (ledger order B0,B1,A0,A1):
  STG_B(0, 0, 0); STG_B(0, 1, 0); STG_A(0, 0, 0); STG_A(0, 1, 0);
  WVM(4);
  STG_B(1, 0, 64); STG_B(1, 1, 64); STG_A(1, 0, 64);
  WVM(6);  // tile0 complete; 6 of tile1 in flight
  BAR();

  bf16x8 aLo[2][4], aHi[2][4], bLo[4], bHi[4];

  for (int i = 0; i < 32; ++i) {
    const bool st = (i < 31);
    const size_t koD1 = (size_t)(2 * i + 1) * 64;
    const size_t koN0 = (size_t)(2 * i + 2) * 64;
    const size_t koN1 = (size_t)(2 * i + 3) * 64;

    // ================= D0 (tile 2i) =================
    // P1: q(m01,n0) reads 12; finish current D1 (A1)
    RDA2(aLo, arA0, 0);
    RDB4(bLo, arB0, 0);
    STG_A(1, 1, koD1);
    WLG(8);
    BAR();
    WLG(0);
    MFQ(aLo, bLo, 0, 0);
    BAR();
    // P2: q(m01,n1) reads 4; stage N0.B0
    RDB4(bHi, arB0, 1);
    if (st) STG_B(0, 0, koN0);
    BAR();
    WLG(0);
    MFQ(aLo, bHi, 0, 1);
    BAR();
    // P3: q(m23,n1) reads 8; stage N0.B1
    RDA2(aHi, arA0, 2);
    if (st) STG_B(0, 1, koN0);
    BAR();
    WLG(0);
    MFQ(aHi, bHi, 1, 1);
    BAR();
    // P4: q(m23,n0) 0 reads; stage N0.A0; vm(6) -> D1 fully landed
    if (st) {
      STG_A(0, 0, koN0);
      WVM(6);
    } else {
      WVM(0);
    }
    BAR();
    MFQ(aHi, bLo, 1, 0);
    BAR();

    // ================= D1 (tile 2i+1) =================
    // P5
    RDA2(aLo, arA1, 0);
    RDB4(bLo, arB1, 0);
    if (st) STG_A(0, 1, koN0);
    WLG(8);
    BAR();
    WLG(0);
    MFQ(aLo, bLo, 0, 0);
    BAR();
    // P6
    RDB4(bHi, arB1, 1);
    if (st) STG_B(1, 0, koN1);
    BAR();
    WLG(0);
    MFQ(aLo, bHi, 0, 1);
    BAR();
    // P7
    RDA2(aHi, arA1, 2);
    if (st) STG_B(1, 1, koN1);
    BAR();
    WLG(0);
    MFQ(aHi, bHi, 1, 1);
    BAR();
    // P8: stage N1.A0; vm(6) -> N0 fully landed
    if (st) {
      STG_A(1, 0, koN1);
      WVM(6);
    }
    BAR();
    MFQ(aHi, bLo, 1, 0);
    BAR();
  }

  // epilogue: 32x32 C/D layout col = lane&31, row = (reg&3)+8*(reg>>2)+4*h2
  float* Cp = out + (size_t)p * 33554432UL +
              ((size_t)(brow * 256 + wm * 128 + 4 * h2)) * 4096 +
              (bcol * 256 + wn * 64 + l31);
#pragma unroll
  for (int mt = 0; mt < 4; ++mt)
#pragma unroll
    for (int nt = 0; nt < 2; ++nt) {
      const f32x16 v = acc[mt][nt];
#pragma unroll
      for (int reg = 0; reg < 16; ++reg) {
        const int row = mt * 32 + (reg & 3) + 8 * (reg >> 2);
        Cp[(size_t)row * 4096 + nt * 32] = v[reg];
      }
    }
}

// ---------------------------------------------------------------------------
extern "C" void kernel_launch(void* const* d_in, const int* in_sizes, int n_in,
                              void* d_out, int out_size, void* d_ws,
                              size_t ws_size, hipStream_t stream) {
  const float* x = (const float*)d_in[0];
  const float* wq = (const float*)d_in[1];
  const float* wk = (const float*)d_in[2];
  const float* wv = (const float*)d_in[3];
  const float* qa = (const float*)d_in[4];
  const float* qb = (const float*)d_in[5];
  const float* ka = (const float*)d_in[6];
  const float* kb = (const float*)d_in[7];
  const float* va = (const float*)d_in[8];
  const float* vb = (const float*)d_in[9];

  unsigned short* xb = (unsigned short*)d_ws;  // 67 MB
  unsigned short* wb = xb + 8192UL * 4096UL;   // 100 MB

  prep_kernel<<<32768, 256, 0, stream>>>(x, wq, wk, wv, qa, qb, ka, kb, va,
                                         vb, xb, wb);
  gemm_kernel<<<1536, 512, 0, stream>>>(xb, wb, (float*)d_out);
}